// Round 12
// baseline (150.833 us; speedup 1.0000x reference)
//
#include <hip/hip_runtime.h>

// SAGEConv: h[50000,64] f32, src/dst[800000] int32, W[128,64] f32, b[64] f32
// out = concat(h, mean_{in-edges}(h[src])) @ W + b
//
// R12 = best measured halves of R9 + R11:
//  - prep: R11's per-tile LDS counting sort, but segments are written
//    wave-cooperatively into per-bucket global regions (contiguous runs,
//    ~7MB effective vs R9's ~51MB per-lane random scatter; 77k reservation
//    atomics as R9).
//  - fused: R9's kernel VERBATIM (measured 50.8us) — contiguous bucket
//    read, single-atomic-pass LDS CSR, 16-lane ushort4 gather, MLP.
//    (R11's per-thread segment-gather A' cost +20us: removed.)
// Lessons: read-side reduction only (R6); scattered 4B writes cost 64B RMW
// lines (R4/R9); per-thread serial segment copies are divergence-bound (R11).

#define IN_FEAT 64
#define KB_SHIFT 6            // 64 nodes per bucket
#define BKN 64
#define CAP 2048              // max pairs per bucket (mean 1024)
#define KPAD 1024             // scan width >= K (782)
#define STILE 4096            // edges per sort tile

__device__ __forceinline__ unsigned short f2bf(float f) {
    unsigned u = __float_as_uint(f);
    return (unsigned short)((u + 0x7FFFu + ((u >> 16) & 1u)) >> 16);
}
__device__ __forceinline__ float bf2f(unsigned short s) {
    return __uint_as_float(((unsigned)s) << 16);
}

// ---- k1: blocks [0,conv_tiles): h->bf16 ; rest: tile sort + segment write --
__global__ __launch_bounds__(512) void sage_prep(
    const float* __restrict__ h, const int* __restrict__ src,
    const int* __restrict__ dst,
    unsigned short* __restrict__ hb, unsigned* __restrict__ pairs,
    int* __restrict__ cursorG,
    int n4, int n_edges, int conv_tiles, int K)
{
    __shared__ int cnt[KPAD];            // 4 KB
    __shared__ int sA[KPAD];             // 4 KB
    __shared__ int sB[KPAD];             // 4 KB
    __shared__ int baseg[KPAD];          // 4 KB (global base per bucket)
    __shared__ unsigned stage[STILE];    // 16 KB
    int t = (int)threadIdx.x;

    if ((int)blockIdx.x < conv_tiles) {
        int tb = blockIdx.x * 8192;
        #pragma unroll
        for (int i = 0; i < 16; ++i) {
            int idx = tb + t + i * 512;            // float4 index
            if (idx < n4) {
                float4 v = ((const float4*)h)[idx];
                ushort4 r;
                r.x = f2bf(v.x); r.y = f2bf(v.y);
                r.z = f2bf(v.z); r.w = f2bf(v.w);
                ((ushort4*)hb)[idx] = r;
            }
        }
        return;
    }

    const int tile  = (int)blockIdx.x - conv_tiles;
    const int ebase = tile * STILE;

    for (int k = t; k < KPAD; k += 512) cnt[k] = 0;
    __syncthreads();

    // count with rank capture
    int kb[8]; unsigned pk[8]; int rk[8];
    #pragma unroll
    for (int i = 0; i < 8; ++i) {
        int e = ebase + t + i * 512;
        kb[i] = -1;
        if (e < n_edges) {
            int d = dst[e], s = src[e];
            kb[i] = d >> KB_SHIFT;
            pk[i] = ((unsigned)s << KB_SHIFT) | (unsigned)(d & (BKN - 1));
            rk[i] = atomicAdd(&cnt[kb[i]], 1);
        }
    }
    __syncthreads();

    // inclusive scan over KPAD counters (ping-pong)
    for (int k = t; k < KPAD; k += 512) sA[k] = cnt[k];
    __syncthreads();
    int* sc = sA; int* sd = sB;
    for (int off = 1; off < KPAD; off <<= 1) {
        for (int k = t; k < KPAD; k += 512)
            sd[k] = sc[k] + ((k >= off) ? sc[k - off] : 0);
        __syncthreads();
        int* tmp = sc; sc = sd; sd = tmp;
    }
    // exclusive offset of bucket k in this tile = sc[k] - cnt[k]

    // LDS scatter into bucket-sorted order + global space reservation
    #pragma unroll
    for (int i = 0; i < 8; ++i)
        if (kb[i] >= 0)
            stage[sc[kb[i]] - cnt[kb[i]] + rk[i]] = pk[i];
    for (int k = t; k < K; k += 512) {
        int len = cnt[k];
        baseg[k] = len ? atomicAdd(&cursorG[k], len) : 0;
    }
    __syncthreads();

    // wave-cooperative segment writes: contiguous runs into bucket regions
    const int w = t >> 6, lane = t & 63;
    for (int k = w; k < K; k += 8) {
        int len = cnt[k];
        if (len == 0) continue;
        int ex = sc[k] - len;
        int gb = baseg[k];
        for (int j = lane; j < len; j += 64) {
            int pos = gb + j;
            if (pos < CAP)                       // safety clamp
                pairs[((size_t)k << 11) + pos] = stage[ex + j];
        }
    }
}

// ---- k2: per-bucket local CSR + gather-mean + MLP (R9 verbatim) ------------
// One block (512 thr, 8 waves) per 64-node bucket. LDS ~50.5KB -> 3 blk/CU.
__global__ __launch_bounds__(512, 6) void sage_fused(
    const unsigned short* __restrict__ hb,
    const float* __restrict__ h,
    const unsigned* __restrict__ pairs,
    const int* __restrict__ cursorG,
    const float* __restrict__ W,     // [128,64] row-major
    const float* __restrict__ bias,
    float* __restrict__ out,
    int n_nodes)
{
    __shared__ float Wsh[128][64];        // 32 KB
    __shared__ float bsh[64];
    __shared__ unsigned short hn[BKN][80];// 10.25 KB (bf16 means)
    __shared__ int   list[CAP];           // 8 KB
    __shared__ int   cnt[BKN];
    __shared__ int   rs[BKN + 1];

    const int t = (int)threadIdx.x;
    {   // stage W: 2048 float4s, 4 per thread
        float4* wd = (float4*)&Wsh[0][0];
        const float4* wsv = (const float4*)W;
        wd[t]        = wsv[t];
        wd[t + 512]  = wsv[t + 512];
        wd[t + 1024] = wsv[t + 1024];
        wd[t + 1536] = wsv[t + 1536];
    }
    if (t < 64) { bsh[t] = bias[t]; cnt[t] = 0; }
    __syncthreads();

    const int b   = (int)blockIdx.x;
    const int nlo = b << KB_SHIFT;
    int m = cursorG[b]; if (m > CAP) m = CAP;
    const unsigned* pb = pairs + ((size_t)b << 11);

    // A: single-atomic-pass local CSR
    unsigned lp[4]; int lr[4];
    #pragma unroll
    for (int i = 0; i < 4; ++i) {
        int idx = t + i * 512;
        lr[i] = -1;
        if (idx < m) {
            lp[i] = pb[idx];
            lr[i] = atomicAdd(&cnt[lp[i] & (BKN - 1)], 1);
        }
    }
    __syncthreads();
    if (t < 64) {            // wave 0 scans the 64 counters
        int v = cnt[t];
        int incl = v;
        #pragma unroll
        for (int off = 1; off < 64; off <<= 1) {
            int x = __shfl_up(incl, off);
            if (t >= off) incl += x;
        }
        rs[t] = incl - v;
        if (t == 63) rs[64] = incl;
    }
    __syncthreads();
    #pragma unroll
    for (int i = 0; i < 4; ++i)
        if (lr[i] >= 0)
            list[rs[lp[i] & (BKN - 1)] + lr[i]] = (int)(lp[i] >> KB_SHIFT);
    __syncthreads();

    const int w    = t >> 6;
    const int lane = t & 63;
    const int sub  = lane >> 4;
    const int q    = lane & 15;

    // B: gather — wave w owns nodes w*8..w*8+7
    for (int i = 0; i < 8; ++i) {
        int nl = w * 8 + i;
        int n  = nlo + nl;
        if (n >= n_nodes) break;               // wave-uniform
        int beg = rs[nl], end = rs[nl + 1];
        float4 acc = make_float4(0.f, 0.f, 0.f, 0.f);
        int e = beg + sub;
        for (; e + 12 < end; e += 16) {        // 4 edges in flight per lane
            int s0 = list[e], s1 = list[e + 4], s2 = list[e + 8], s3 = list[e + 12];
            const ushort4 u0 = *(const ushort4*)(hb + ((size_t)s0 << 6) + q * 4);
            const ushort4 u1 = *(const ushort4*)(hb + ((size_t)s1 << 6) + q * 4);
            const ushort4 u2 = *(const ushort4*)(hb + ((size_t)s2 << 6) + q * 4);
            const ushort4 u3 = *(const ushort4*)(hb + ((size_t)s3 << 6) + q * 4);
            acc.x += (bf2f(u0.x) + bf2f(u1.x)) + (bf2f(u2.x) + bf2f(u3.x));
            acc.y += (bf2f(u0.y) + bf2f(u1.y)) + (bf2f(u2.y) + bf2f(u3.y));
            acc.z += (bf2f(u0.z) + bf2f(u1.z)) + (bf2f(u2.z) + bf2f(u3.z));
            acc.w += (bf2f(u0.w) + bf2f(u1.w)) + (bf2f(u2.w) + bf2f(u3.w));
        }
        for (; e + 4 < end; e += 8) {
            int s0 = list[e], s1 = list[e + 4];
            const ushort4 u0 = *(const ushort4*)(hb + ((size_t)s0 << 6) + q * 4);
            const ushort4 u1 = *(const ushort4*)(hb + ((size_t)s1 << 6) + q * 4);
            acc.x += bf2f(u0.x) + bf2f(u1.x);
            acc.y += bf2f(u0.y) + bf2f(u1.y);
            acc.z += bf2f(u0.z) + bf2f(u1.z);
            acc.w += bf2f(u0.w) + bf2f(u1.w);
        }
        if (e < end) {
            int s0 = list[e];
            const ushort4 u0 = *(const ushort4*)(hb + ((size_t)s0 << 6) + q * 4);
            acc.x += bf2f(u0.x); acc.y += bf2f(u0.y);
            acc.z += bf2f(u0.z); acc.w += bf2f(u0.w);
        }
        #pragma unroll
        for (int mm = 16; mm < 64; mm <<= 1) {
            acc.x += __shfl_xor(acc.x, mm);
            acc.y += __shfl_xor(acc.y, mm);
            acc.z += __shfl_xor(acc.z, mm);
            acc.w += __shfl_xor(acc.w, mm);
        }
        int deg = end - beg;
        float inv = (deg > 0) ? (1.0f / (float)deg) : 0.f;
        if (sub == 0) {
            ushort4 r;
            r.x = f2bf(acc.x * inv); r.y = f2bf(acc.y * inv);
            r.z = f2bf(acc.z * inv); r.w = f2bf(acc.w * inv);
            *(ushort4*)&hn[nl][q * 4] = r;
        }
    }
    __builtin_amdgcn_wave_barrier();   // hn is wave-private; scheduling fence

    // C: MLP — wave w, pass p: node w*8 + p*4 + sub
    #pragma unroll
    for (int p = 0; p < 2; ++p) {
        int nl = w * 8 + p * 4 + sub;
        int n  = nlo + nl;
        if (n < n_nodes) {
            const float* hrow = h + ((size_t)n << 6);
            float4 o = ((const float4*)bsh)[q];
            #pragma unroll
            for (int k4 = 0; k4 < 16; ++k4) {
                const float4 hq = *(const float4*)(hrow + k4 * 4);   // bcast x16
                #pragma unroll
                for (int c = 0; c < 4; ++c) {
                    float hv = (&hq.x)[c];
                    const float4 wv = *(const float4*)&Wsh[k4 * 4 + c][q * 4];
                    o.x = fmaf(hv, wv.x, o.x);
                    o.y = fmaf(hv, wv.y, o.y);
                    o.z = fmaf(hv, wv.z, o.z);
                    o.w = fmaf(hv, wv.w, o.w);
                }
            }
            #pragma unroll 16
            for (int k = 0; k < 64; ++k) {
                float hv = bf2f(hn[nl][k]);
                const float4 wv = *(const float4*)&Wsh[64 + k][q * 4];
                o.x = fmaf(hv, wv.x, o.x);
                o.y = fmaf(hv, wv.y, o.y);
                o.z = fmaf(hv, wv.z, o.z);
                o.w = fmaf(hv, wv.w, o.w);
            }
            *(float4*)(out + ((size_t)n << 6) + q * 4) = o;
        }
    }
}

extern "C" void kernel_launch(void* const* d_in, const int* in_sizes, int n_in,
                              void* d_out, int out_size, void* d_ws, size_t ws_size,
                              hipStream_t stream) {
    const float* h   = (const float*)d_in[0];
    const int*   src = (const int*)d_in[1];
    const int*   dst = (const int*)d_in[2];
    const float* W   = (const float*)d_in[3];
    const float* b   = (const float*)d_in[4];
    float* out = (float*)d_out;

    const int n_nodes = in_sizes[0] / IN_FEAT;
    const int n_edges = in_sizes[1];
    const int K  = (n_nodes + BKN - 1) >> KB_SHIFT;    // 782
    const int n4 = n_nodes * (IN_FEAT / 4);            // 800000 float4s

    // ws: hb[N*64 ushort] | pairs[K*CAP u32] | cursorG[K]
    unsigned short* hb = (unsigned short*)d_ws;
    unsigned* pairs    = (unsigned*)(hb + (size_t)n_nodes * IN_FEAT);
    int* cursorG       = (int*)(pairs + (size_t)K * CAP);

    hipMemsetAsync(cursorG, 0, (size_t)K * sizeof(int), stream);

    const int conv_tiles = (n4 + 8191) / 8192;             // 98
    const int n_stiles   = (n_edges + STILE - 1) / STILE;  // 196
    sage_prep<<<conv_tiles + n_stiles, 512, 0, stream>>>(
        h, src, dst, hb, pairs, cursorG, n4, n_edges, conv_tiles, K);
    sage_fused<<<K, 512, 0, stream>>>(hb, h, pairs, cursorG, W, b, out, n_nodes);
}

// Round 13
// 125.628 us; speedup vs baseline: 1.2006x; 1.2006x over previous
//
#include <hip/hip_runtime.h>

// SAGEConv: h[50000,64] f32, src/dst[800000] int32, W[128,64] f32, b[64] f32
// out = concat(h, mean_{in-edges}(h[src])) @ W + b
//
// R13: prep = R9 verbatim (direct rank-capture scatter, ~28us measured).
//      fused = R9's algorithm at 1024 threads/block: 2 blocks/CU x 16 waves
//      (32 waves = full occupancy) and only 4 serialized nodes per wave
//      (vs 8) — the per-wave latency chain is the measured binding
//      constraint (6 variants plateaued 46-52us; best was R7's 46.2 at
//      1024 threads).
// Accounting note (R12 post-mortem): harness ws re-poison (~46us, 268MB
// fillBuffer) + memset + gaps ~= 54us fixed; kernel-controllable part is
// prep + fused only.
// Lessons: read-side reduction only (R6); scattered 4B writes OK at ~28us
// when per-lane (R9) but LDS counting-sort + segment writes are slower
// (R12); per-thread serial segment copies are divergence-bound (R11).

#define IN_FEAT 64
#define KB_SHIFT 6            // 64 nodes per bucket
#define BKN 64
#define CAP 2048              // max pairs per bucket (mean 1024)
#define KMAX 1024             // supports n_nodes <= 65536

__device__ __forceinline__ unsigned short f2bf(float f) {
    unsigned u = __float_as_uint(f);
    return (unsigned short)((u + 0x7FFFu + ((u >> 16) & 1u)) >> 16);
}
__device__ __forceinline__ float bf2f(unsigned short s) {
    return __uint_as_float(((unsigned)s) << 16);
}

// ---- k1: blocks [0,conv_tiles): h->bf16 ; rest: bucket the edges (R9) ------
__global__ __launch_bounds__(512) void sage_prep(
    const float* __restrict__ h, const int* __restrict__ src,
    const int* __restrict__ dst,
    unsigned short* __restrict__ hb, unsigned* __restrict__ pairs,
    int* __restrict__ cursorG,
    int n4, int n_edges, int conv_tiles, int K)
{
    __shared__ int cnt[KMAX];
    __shared__ int base[KMAX];
    int t = (int)threadIdx.x;

    if ((int)blockIdx.x < conv_tiles) {
        int tb = blockIdx.x * 8192;
        #pragma unroll
        for (int i = 0; i < 16; ++i) {
            int idx = tb + t + i * 512;            // float4 index
            if (idx < n4) {
                float4 v = ((const float4*)h)[idx];
                ushort4 r;
                r.x = f2bf(v.x); r.y = f2bf(v.y);
                r.z = f2bf(v.z); r.w = f2bf(v.w);
                ((ushort4*)hb)[idx] = r;
            }
        }
    } else {
        for (int k = t; k < K; k += 512) cnt[k] = 0;
        __syncthreads();
        int tb = ((int)blockIdx.x - conv_tiles) * 8192;
        int kb[16]; unsigned pk[16]; int rk[16];
        #pragma unroll 4
        for (int i = 0; i < 16; ++i) {
            int e = tb + t + i * 512;
            kb[i] = -1;
            if (e < n_edges) {
                int d = dst[e], s = src[e];
                int k = d >> KB_SHIFT;
                kb[i] = k;
                pk[i] = ((unsigned)s << KB_SHIFT) | (unsigned)(d & (BKN - 1));
                rk[i] = atomicAdd(&cnt[k], 1);     // rank within (tile,bucket)
            }
        }
        __syncthreads();
        for (int k = t; k < K; k += 512) {
            int c = cnt[k];
            base[k] = c ? atomicAdd(&cursorG[k], c) : 0;
        }
        __syncthreads();
        #pragma unroll 4
        for (int i = 0; i < 16; ++i) {
            if (kb[i] >= 0) {
                int pos = base[kb[i]] + rk[i];
                if (pos < CAP)                      // safety clamp
                    pairs[((size_t)kb[i] << 11) + pos] = pk[i];
            }
        }
    }
}

// ---- k2: per-bucket local CSR + gather-mean + MLP, 1024 threads ------------
// One block (1024 thr, 16 waves) per 64-node bucket; 2 blocks/CU (LDS
// ~50.8KB), 32 waves = full occupancy. Wave w owns nodes w*4..w*4+3 for
// gather AND MLP (wave-private hn, no in-loop barriers after CSR build).
__global__ __launch_bounds__(1024, 8) void sage_fused(
    const unsigned short* __restrict__ hb,
    const float* __restrict__ h,
    const unsigned* __restrict__ pairs,
    const int* __restrict__ cursorG,
    const float* __restrict__ W,     // [128,64] row-major
    const float* __restrict__ bias,
    float* __restrict__ out,
    int n_nodes)
{
    __shared__ float Wsh[128][64];        // 32 KB
    __shared__ float bsh[64];
    __shared__ unsigned short hn[BKN][80];// 10.25 KB (bf16 means)
    __shared__ int   list[CAP];           // 8 KB
    __shared__ int   cnt[BKN];
    __shared__ int   rs[BKN + 1];

    const int t = (int)threadIdx.x;
    {   // stage W: 2048 float4s, 2 per thread
        float4* wd = (float4*)&Wsh[0][0];
        const float4* wsv = (const float4*)W;
        wd[t]        = wsv[t];
        wd[t + 1024] = wsv[t + 1024];
    }
    if (t < 64) { bsh[t] = bias[t]; cnt[t] = 0; }
    __syncthreads();

    const int b   = (int)blockIdx.x;
    const int nlo = b << KB_SHIFT;
    int m = cursorG[b]; if (m > CAP) m = CAP;
    const unsigned* pb = pairs + ((size_t)b << 11);

    // A: single-atomic-pass local CSR (2 pairs per thread)
    unsigned lp[2]; int lr[2];
    #pragma unroll
    for (int i = 0; i < 2; ++i) {
        int idx = t + i * 1024;
        lr[i] = -1;
        if (idx < m) {
            lp[i] = pb[idx];
            lr[i] = atomicAdd(&cnt[lp[i] & (BKN - 1)], 1);
        }
    }
    __syncthreads();
    if (t < 64) {            // wave 0 scans the 64 counters
        int v = cnt[t];
        int incl = v;
        #pragma unroll
        for (int off = 1; off < 64; off <<= 1) {
            int x = __shfl_up(incl, off);
            if (t >= off) incl += x;
        }
        rs[t] = incl - v;
        if (t == 63) rs[64] = incl;
    }
    __syncthreads();
    #pragma unroll
    for (int i = 0; i < 2; ++i)
        if (lr[i] >= 0)
            list[rs[lp[i] & (BKN - 1)] + lr[i]] = (int)(lp[i] >> KB_SHIFT);
    __syncthreads();

    const int w    = t >> 6;         // wave 0..15
    const int lane = t & 63;
    const int sub  = lane >> 4;
    const int q    = lane & 15;

    // B: gather — wave w owns nodes w*4..w*4+3
    #pragma unroll
    for (int i = 0; i < 4; ++i) {
        int nl = w * 4 + i;
        int n  = nlo + nl;
        if (n >= n_nodes) break;               // wave-uniform
        int beg = rs[nl], end = rs[nl + 1];
        float4 acc = make_float4(0.f, 0.f, 0.f, 0.f);
        int e = beg + sub;
        for (; e + 12 < end; e += 16) {        // 4 edges in flight per lane
            int s0 = list[e], s1 = list[e + 4], s2 = list[e + 8], s3 = list[e + 12];
            const ushort4 u0 = *(const ushort4*)(hb + ((size_t)s0 << 6) + q * 4);
            const ushort4 u1 = *(const ushort4*)(hb + ((size_t)s1 << 6) + q * 4);
            const ushort4 u2 = *(const ushort4*)(hb + ((size_t)s2 << 6) + q * 4);
            const ushort4 u3 = *(const ushort4*)(hb + ((size_t)s3 << 6) + q * 4);
            acc.x += (bf2f(u0.x) + bf2f(u1.x)) + (bf2f(u2.x) + bf2f(u3.x));
            acc.y += (bf2f(u0.y) + bf2f(u1.y)) + (bf2f(u2.y) + bf2f(u3.y));
            acc.z += (bf2f(u0.z) + bf2f(u1.z)) + (bf2f(u2.z) + bf2f(u3.z));
            acc.w += (bf2f(u0.w) + bf2f(u1.w)) + (bf2f(u2.w) + bf2f(u3.w));
        }
        for (; e + 4 < end; e += 8) {
            int s0 = list[e], s1 = list[e + 4];
            const ushort4 u0 = *(const ushort4*)(hb + ((size_t)s0 << 6) + q * 4);
            const ushort4 u1 = *(const ushort4*)(hb + ((size_t)s1 << 6) + q * 4);
            acc.x += bf2f(u0.x) + bf2f(u1.x);
            acc.y += bf2f(u0.y) + bf2f(u1.y);
            acc.z += bf2f(u0.z) + bf2f(u1.z);
            acc.w += bf2f(u0.w) + bf2f(u1.w);
        }
        if (e < end) {
            int s0 = list[e];
            const ushort4 u0 = *(const ushort4*)(hb + ((size_t)s0 << 6) + q * 4);
            acc.x += bf2f(u0.x); acc.y += bf2f(u0.y);
            acc.z += bf2f(u0.z); acc.w += bf2f(u0.w);
        }
        #pragma unroll
        for (int mm = 16; mm < 64; mm <<= 1) {
            acc.x += __shfl_xor(acc.x, mm);
            acc.y += __shfl_xor(acc.y, mm);
            acc.z += __shfl_xor(acc.z, mm);
            acc.w += __shfl_xor(acc.w, mm);
        }
        int deg = end - beg;
        float inv = (deg > 0) ? (1.0f / (float)deg) : 0.f;
        if (sub == 0) {
            ushort4 r;
            r.x = f2bf(acc.x * inv); r.y = f2bf(acc.y * inv);
            r.z = f2bf(acc.z * inv); r.w = f2bf(acc.w * inv);
            *(ushort4*)&hn[nl][q * 4] = r;
        }
    }
    __builtin_amdgcn_wave_barrier();   // hn is wave-private; scheduling fence

    // C: MLP — wave w: node w*4 + sub, cols 4q..4q+3 (single pass)
    {
        int nl = w * 4 + sub;
        int n  = nlo + nl;
        if (n < n_nodes) {
            const float* hrow = h + ((size_t)n << 6);
            float4 o = ((const float4*)bsh)[q];
            #pragma unroll
            for (int k4 = 0; k4 < 16; ++k4) {
                const float4 hq = *(const float4*)(hrow + k4 * 4);   // bcast x16
                #pragma unroll
                for (int c = 0; c < 4; ++c) {
                    float hv = (&hq.x)[c];
                    const float4 wv = *(const float4*)&Wsh[k4 * 4 + c][q * 4];
                    o.x = fmaf(hv, wv.x, o.x);
                    o.y = fmaf(hv, wv.y, o.y);
                    o.z = fmaf(hv, wv.z, o.z);
                    o.w = fmaf(hv, wv.w, o.w);
                }
            }
            #pragma unroll 16
            for (int k = 0; k < 64; ++k) {
                float hv = bf2f(hn[nl][k]);
                const float4 wv = *(const float4*)&Wsh[64 + k][q * 4];
                o.x = fmaf(hv, wv.x, o.x);
                o.y = fmaf(hv, wv.y, o.y);
                o.z = fmaf(hv, wv.z, o.z);
                o.w = fmaf(hv, wv.w, o.w);
            }
            *(float4*)(out + ((size_t)n << 6) + q * 4) = o;
        }
    }
}

extern "C" void kernel_launch(void* const* d_in, const int* in_sizes, int n_in,
                              void* d_out, int out_size, void* d_ws, size_t ws_size,
                              hipStream_t stream) {
    const float* h   = (const float*)d_in[0];
    const int*   src = (const int*)d_in[1];
    const int*   dst = (const int*)d_in[2];
    const float* W   = (const float*)d_in[3];
    const float* b   = (const float*)d_in[4];
    float* out = (float*)d_out;

    const int n_nodes = in_sizes[0] / IN_FEAT;
    const int n_edges = in_sizes[1];
    const int K  = (n_nodes + BKN - 1) >> KB_SHIFT;    // 782
    const int n4 = n_nodes * (IN_FEAT / 4);            // 800000 float4s

    // ws: hb[N*64 ushort] | pairs[K*CAP u32] | cursorG[K]
    unsigned short* hb = (unsigned short*)d_ws;
    unsigned* pairs    = (unsigned*)(hb + (size_t)n_nodes * IN_FEAT);
    int* cursorG       = (int*)(pairs + (size_t)K * CAP);

    hipMemsetAsync(cursorG, 0, (size_t)K * sizeof(int), stream);

    const int conv_tiles   = (n4 + 8191) / 8192;       // 98
    const int bucket_tiles = (n_edges + 8191) / 8192;  // 98
    sage_prep<<<conv_tiles + bucket_tiles, 512, 0, stream>>>(
        h, src, dst, hb, pairs, cursorG, n4, n_edges, conv_tiles, K);
    sage_fused<<<K, 1024, 0, stream>>>(hb, h, pairs, cursorG, W, b, out, n_nodes);
}

// Round 14
// 113.364 us; speedup vs baseline: 1.3305x; 1.1082x over previous
//
#include <hip/hip_runtime.h>

// SAGEConv: h[50000,64] f32, src/dst[800000] int32, W[128,64] f32, b[64] f32
// out = concat(h, mean_{in-edges}(h[src])) @ W + b
//
// R14: prep = R13 verbatim. fused: MLP replaced by MFMA (G10) —
//   per block: out[64,64] = A[64,128]@Wt + b, A = [self_bf16 | hn_bf16] in
//   LDS, Wt = W transposed to bf16 [64][128]. 16 waves x one 16x16 C-tile
//   x 4 K-steps of mfma_f32_16x16x32_bf16. Kills the 16x-redundant 1MB/block
//   Wsh LDS traffic + f32 FMA chain of the VALU MLP.
// Fragment layouts (guide, HW-verified m89/m91/m120):
//   A: lane holds A[m=lane&15][k=quad*8+j], j=0..7 (contiguous 16B)
//   B: lane holds B[k=quad*8+j][n=lane&15] -> read from Wt[n][k] contiguous
//   C/D: col=lane&15, row=quad*4+reg
// Lessons: read-side reduction only (R6); R9 prep scatter is the measured
// fastest CSR build (R12 sort slower, R11 segment-gather slower).

#define IN_FEAT 64
#define KB_SHIFT 6            // 64 nodes per bucket
#define BKN 64
#define CAP 2048              // max pairs per bucket (mean 1024)
#define KMAX 1024             // supports n_nodes <= 65536
#define AP 136                // A/Wt row pad (shorts): 272B rows, 16B-aligned

typedef __attribute__((ext_vector_type(8))) short short8;   // 8 bf16 = 4 VGPR
typedef __attribute__((ext_vector_type(4))) float f32x4;

__device__ __forceinline__ unsigned short f2bf(float f) {
    unsigned u = __float_as_uint(f);
    return (unsigned short)((u + 0x7FFFu + ((u >> 16) & 1u)) >> 16);
}
__device__ __forceinline__ float bf2f(unsigned short s) {
    return __uint_as_float(((unsigned)s) << 16);
}

// ---- k1: blocks [0,conv_tiles): h->bf16 ; rest: bucket the edges (R9) ------
__global__ __launch_bounds__(512) void sage_prep(
    const float* __restrict__ h, const int* __restrict__ src,
    const int* __restrict__ dst,
    unsigned short* __restrict__ hb, unsigned* __restrict__ pairs,
    int* __restrict__ cursorG,
    int n4, int n_edges, int conv_tiles, int K)
{
    __shared__ int cnt[KMAX];
    __shared__ int base[KMAX];
    int t = (int)threadIdx.x;

    if ((int)blockIdx.x < conv_tiles) {
        int tb = blockIdx.x * 8192;
        #pragma unroll
        for (int i = 0; i < 16; ++i) {
            int idx = tb + t + i * 512;            // float4 index
            if (idx < n4) {
                float4 v = ((const float4*)h)[idx];
                ushort4 r;
                r.x = f2bf(v.x); r.y = f2bf(v.y);
                r.z = f2bf(v.z); r.w = f2bf(v.w);
                ((ushort4*)hb)[idx] = r;
            }
        }
    } else {
        for (int k = t; k < K; k += 512) cnt[k] = 0;
        __syncthreads();
        int tb = ((int)blockIdx.x - conv_tiles) * 8192;
        int kb[16]; unsigned pk[16]; int rk[16];
        #pragma unroll 4
        for (int i = 0; i < 16; ++i) {
            int e = tb + t + i * 512;
            kb[i] = -1;
            if (e < n_edges) {
                int d = dst[e], s = src[e];
                int k = d >> KB_SHIFT;
                kb[i] = k;
                pk[i] = ((unsigned)s << KB_SHIFT) | (unsigned)(d & (BKN - 1));
                rk[i] = atomicAdd(&cnt[k], 1);     // rank within (tile,bucket)
            }
        }
        __syncthreads();
        for (int k = t; k < K; k += 512) {
            int c = cnt[k];
            base[k] = c ? atomicAdd(&cursorG[k], c) : 0;
        }
        __syncthreads();
        #pragma unroll 4
        for (int i = 0; i < 16; ++i) {
            if (kb[i] >= 0) {
                int pos = base[kb[i]] + rk[i];
                if (pos < CAP)                      // safety clamp
                    pairs[((size_t)kb[i] << 11) + pos] = pk[i];
            }
        }
    }
}

// ---- k2: local CSR + gather-mean + MFMA output -----------------------------
// One block (1024 thr, 16 waves) per 64-node bucket; LDS ~44KB, 2 blocks/CU
// (thread-capped), 32 waves/CU.
__global__ __launch_bounds__(1024, 8) void sage_fused(
    const unsigned short* __restrict__ hb,
    const unsigned* __restrict__ pairs,
    const int* __restrict__ cursorG,
    const float* __restrict__ W,     // [128,64] row-major f32
    const float* __restrict__ bias,
    float* __restrict__ out,
    int n_nodes)
{
    __shared__ unsigned short Wt[64][AP];   // bf16 W^T: Wt[n][k], 17.4 KB
    __shared__ unsigned short A[BKN][AP];   // [self(0:64) | hn(64:128)], 17.4 KB
    __shared__ float bsh[64];
    __shared__ int   list[CAP];             // 8 KB
    __shared__ int   cnt[BKN];
    __shared__ int   rs[BKN + 1];

    const int t = (int)threadIdx.x;
    const int b   = (int)blockIdx.x;
    const int nlo = b << KB_SHIFT;

    // stage Wt (bf16 transpose of W): 8192 elems, 8 per thread
    #pragma unroll
    for (int i = 0; i < 8; ++i) {
        int idx = t + i * 1024;              // idx = k*64 + n
        int k = idx >> 6, n = idx & 63;
        Wt[n][k] = f2bf(W[idx]);
    }
    // stage A self half from hb: 64 rows x 64 shorts, ushort4 per thread
    {
        int nl = t >> 4, c4 = (t & 15) * 4;
        if (nlo + nl < n_nodes)
            *(ushort4*)&A[nl][c4] =
                *(const ushort4*)(hb + ((size_t)(nlo + nl) << 6) + c4);
    }
    if (t < 64) { bsh[t] = bias[t]; cnt[t] = 0; }
    __syncthreads();

    int m = cursorG[b]; if (m > CAP) m = CAP;
    const unsigned* pb = pairs + ((size_t)b << 11);

    // A-phase: single-atomic-pass local CSR (2 pairs per thread)
    unsigned lp[2]; int lr[2];
    #pragma unroll
    for (int i = 0; i < 2; ++i) {
        int idx = t + i * 1024;
        lr[i] = -1;
        if (idx < m) {
            lp[i] = pb[idx];
            lr[i] = atomicAdd(&cnt[lp[i] & (BKN - 1)], 1);
        }
    }
    __syncthreads();
    if (t < 64) {            // wave 0 scans the 64 counters
        int v = cnt[t];
        int incl = v;
        #pragma unroll
        for (int off = 1; off < 64; off <<= 1) {
            int x = __shfl_up(incl, off);
            if (t >= off) incl += x;
        }
        rs[t] = incl - v;
        if (t == 63) rs[64] = incl;
    }
    __syncthreads();
    #pragma unroll
    for (int i = 0; i < 2; ++i)
        if (lr[i] >= 0)
            list[rs[lp[i] & (BKN - 1)] + lr[i]] = (int)(lp[i] >> KB_SHIFT);
    __syncthreads();

    const int w    = t >> 6;         // wave 0..15
    const int lane = t & 63;
    const int sub  = lane >> 4;
    const int q    = lane & 15;

    // B-phase: gather — wave w owns nodes w*4..w*4+3, mean -> A[nl][64+...]
    #pragma unroll
    for (int i = 0; i < 4; ++i) {
        int nl = w * 4 + i;
        int n  = nlo + nl;
        if (n >= n_nodes) break;               // wave-uniform
        int beg = rs[nl], end = rs[nl + 1];
        float4 acc = make_float4(0.f, 0.f, 0.f, 0.f);
        int e = beg + sub;
        for (; e + 12 < end; e += 16) {        // 4 edges in flight per lane
            int s0 = list[e], s1 = list[e + 4], s2 = list[e + 8], s3 = list[e + 12];
            const ushort4 u0 = *(const ushort4*)(hb + ((size_t)s0 << 6) + q * 4);
            const ushort4 u1 = *(const ushort4*)(hb + ((size_t)s1 << 6) + q * 4);
            const ushort4 u2 = *(const ushort4*)(hb + ((size_t)s2 << 6) + q * 4);
            const ushort4 u3 = *(const ushort4*)(hb + ((size_t)s3 << 6) + q * 4);
            acc.x += (bf2f(u0.x) + bf2f(u1.x)) + (bf2f(u2.x) + bf2f(u3.x));
            acc.y += (bf2f(u0.y) + bf2f(u1.y)) + (bf2f(u2.y) + bf2f(u3.y));
            acc.z += (bf2f(u0.z) + bf2f(u1.z)) + (bf2f(u2.z) + bf2f(u3.z));
            acc.w += (bf2f(u0.w) + bf2f(u1.w)) + (bf2f(u2.w) + bf2f(u3.w));
        }
        for (; e + 4 < end; e += 8) {
            int s0 = list[e], s1 = list[e + 4];
            const ushort4 u0 = *(const ushort4*)(hb + ((size_t)s0 << 6) + q * 4);
            const ushort4 u1 = *(const ushort4*)(hb + ((size_t)s1 << 6) + q * 4);
            acc.x += bf2f(u0.x) + bf2f(u1.x);
            acc.y += bf2f(u0.y) + bf2f(u1.y);
            acc.z += bf2f(u0.z) + bf2f(u1.z);
            acc.w += bf2f(u0.w) + bf2f(u1.w);
        }
        if (e < end) {
            int s0 = list[e];
            const ushort4 u0 = *(const ushort4*)(hb + ((size_t)s0 << 6) + q * 4);
            acc.x += bf2f(u0.x); acc.y += bf2f(u0.y);
            acc.z += bf2f(u0.z); acc.w += bf2f(u0.w);
        }
        #pragma unroll
        for (int mm = 16; mm < 64; mm <<= 1) {
            acc.x += __shfl_xor(acc.x, mm);
            acc.y += __shfl_xor(acc.y, mm);
            acc.z += __shfl_xor(acc.z, mm);
            acc.w += __shfl_xor(acc.w, mm);
        }
        int deg = end - beg;
        float inv = (deg > 0) ? (1.0f / (float)deg) : 0.f;
        if (sub == 0) {
            ushort4 r;
            r.x = f2bf(acc.x * inv); r.y = f2bf(acc.y * inv);
            r.z = f2bf(acc.z * inv); r.w = f2bf(acc.w * inv);
            *(ushort4*)&A[nl][64 + q * 4] = r;
        }
    }
    __syncthreads();   // A's hn half is written by all waves; MFMA reads all

    // C-phase: MFMA — wave w computes C-tile (mt = w>>2, nt = w&3)
    {
        const int mt = w >> 2, nt = w & 3;
        const int quad = lane >> 4, l16 = lane & 15;
        f32x4 acc;
        float bv = bsh[nt * 16 + l16];
        acc[0] = bv; acc[1] = bv; acc[2] = bv; acc[3] = bv;
        #pragma unroll
        for (int ks = 0; ks < 4; ++ks) {
            const short8 aF = *(const short8*)&A[mt * 16 + l16][ks * 32 + quad * 8];
            const short8 bF = *(const short8*)&Wt[nt * 16 + l16][ks * 32 + quad * 8];
            acc = __builtin_amdgcn_mfma_f32_16x16x32_bf16(aF, bF, acc, 0, 0, 0);
        }
        #pragma unroll
        for (int r = 0; r < 4; ++r) {
            int row = nlo + mt * 16 + quad * 4 + r;
            if (row < n_nodes)
                out[((size_t)row << 6) + nt * 16 + l16] = acc[r];
        }
    }
}

extern "C" void kernel_launch(void* const* d_in, const int* in_sizes, int n_in,
                              void* d_out, int out_size, void* d_ws, size_t ws_size,
                              hipStream_t stream) {
    const float* h   = (const float*)d_in[0];
    const int*   src = (const int*)d_in[1];
    const int*   dst = (const int*)d_in[2];
    const float* W   = (const float*)d_in[3];
    const float* b   = (const float*)d_in[4];
    float* out = (float*)d_out;

    const int n_nodes = in_sizes[0] / IN_FEAT;
    const int n_edges = in_sizes[1];
    const int K  = (n_nodes + BKN - 1) >> KB_SHIFT;    // 782
    const int n4 = n_nodes * (IN_FEAT / 4);            // 800000 float4s

    // ws: hb[N*64 ushort] | pairs[K*CAP u32] | cursorG[K]
    unsigned short* hb = (unsigned short*)d_ws;
    unsigned* pairs    = (unsigned*)(hb + (size_t)n_nodes * IN_FEAT);
    int* cursorG       = (int*)(pairs + (size_t)K * CAP);

    hipMemsetAsync(cursorG, 0, (size_t)K * sizeof(int), stream);

    const int conv_tiles   = (n4 + 8191) / 8192;       // 98
    const int bucket_tiles = (n_edges + 8191) / 8192;  // 98
    sage_prep<<<conv_tiles + bucket_tiles, 512, 0, stream>>>(
        h, src, dst, hb, pairs, cursorG, n4, n_edges, conv_tiles, K);
    sage_fused<<<K, 1024, 0, stream>>>(hb, pairs, cursorG, W, b, out, n_nodes);
}